// Round 1
// baseline (1865.286 us; speedup 1.0000x reference)
//
#include <hip/hip_runtime.h>
#include <hip/hip_bf16.h>

// Problem constants (from reference):
// B=64 (time axis of the LSTM due to torch batch_first quirk), L=64 (only col 63 used),
// N=256, C=8, Ct=4 -> NQ=1024 sequences, H=128, 4H=512, RH1=128, RH2=64, S=4.

__device__ __forceinline__ float sigf(float x)   { return 1.0f / (1.0f + __expf(-x)); }
__device__ __forceinline__ float tanh_f(float x) { return 1.0f - 2.0f / (__expf(2.0f * x) + 1.0f); }

// ---------------- init: cur <- x[:, 63, :, :]  (B,NQ,C) flat ----------------
__global__ void init_cur_k(const float* __restrict__ x, float* __restrict__ cur)
{
    int i   = blockIdx.x * 256 + threadIdx.x;   // 0 .. 524287
    int b   = i >> 13;                          // /8192
    int rem = i & 8191;
    cur[i] = x[(size_t)b * 524288 + 63 * 8192 + rem];
}

// ---------------- LSTM scan for one roll ----------------
// grid 256 wgs x 512 thr. wg owns sequences q0..q0+3 for all 64 steps.
// Thread t owns gate row g=t: W_hh[g][*] in 128 VGPRs, W_ih[g][*] in 8 VGPRs.
// h lives in LDS (broadcast reads); c-state per (s,j) thread in a register.
__global__ __launch_bounds__(512, 1) void lstm_roll_k(
    const float* __restrict__ cur, const float* __restrict__ W_ih,
    const float* __restrict__ W_hh, const float* __restrict__ b_ih,
    const float* __restrict__ b_hh, float* __restrict__ hs)
{
    __shared__ __align__(16) float hL[4][128];   // h per sequence
    __shared__ float pre[4][512];                // gate preactivations

    const int t  = threadIdx.x;                  // gate row 0..511
    const int q0 = blockIdx.x * 4;

    float wih[8];
#pragma unroll
    for (int c = 0; c < 8; ++c) wih[c] = W_ih[t * 8 + c];
    const float bsum = b_ih[t] + b_hh[t];

    float w[128];
#pragma unroll
    for (int k = 0; k < 128; ++k) w[k] = W_hh[t * 128 + k];

    ((float*)hL)[t] = 0.0f;                      // 4*128 == 512 == blockDim
    float cc = 0.0f;
    const int s2 = t >> 7, j2 = t & 127;         // gate-math ownership (seq, h-elem)
    __syncthreads();

    for (int step = 0; step < 64; ++step) {
        // ---- phase 1: preact[g][s] = bsum + x.W_ih + h.W_hh ----
        const float* __restrict__ xr = cur + step * 8192 + q0 * 8;  // uniform -> s_loads
        float a0 = bsum, a1 = bsum, a2 = bsum, a3 = bsum;
#pragma unroll
        for (int c = 0; c < 8; ++c) {
            float wc = wih[c];
            a0 += xr[c] * wc; a1 += xr[8 + c] * wc;
            a2 += xr[16 + c] * wc; a3 += xr[24 + c] * wc;
        }
#pragma unroll
        for (int jq = 0; jq < 32; ++jq) {
            float4 h0 = *(const float4*)&hL[0][jq * 4];
            float4 h1 = *(const float4*)&hL[1][jq * 4];
            float4 h2 = *(const float4*)&hL[2][jq * 4];
            float4 h3 = *(const float4*)&hL[3][jq * 4];
            float w0 = w[jq * 4 + 0], w1 = w[jq * 4 + 1];
            float w2 = w[jq * 4 + 2], w3 = w[jq * 4 + 3];
            a0 += h0.x * w0 + h0.y * w1 + h0.z * w2 + h0.w * w3;
            a1 += h1.x * w0 + h1.y * w1 + h1.z * w2 + h1.w * w3;
            a2 += h2.x * w0 + h2.y * w1 + h2.z * w2 + h2.w * w3;
            a3 += h3.x * w0 + h3.y * w1 + h3.z * w2 + h3.w * w3;
        }
        pre[0][t] = a0; pre[1][t] = a1; pre[2][t] = a2; pre[3][t] = a3;
        __syncthreads();

        // ---- phase 2: gates (torch order i,f,g,o), update c,h ----
        float pi = pre[s2][j2],       pf = pre[s2][128 + j2];
        float pg = pre[s2][256 + j2], po = pre[s2][384 + j2];
        cc = sigf(pf) * cc + sigf(pi) * tanh_f(pg);
        float hv = sigf(po) * tanh_f(cc);
        hL[s2][j2] = hv;   // safe: all phase-1 reads completed before prior barrier
        hs[(size_t)(step * 1024 + q0 + s2) * 128 + j2] = hv;
        __syncthreads();
    }
}

// ---------------- MLP + head for one roll ----------------
// grid 256 wgs x 256 thr; each wg stages W1 in LDS once, then 16 chunks of 16 items.
// items are (b, q): q = n*4+ct; 16 consecutive q == 4 full n-groups (no atomics).
__global__ __launch_bounds__(256, 1) void mlp_roll_k(
    const float* __restrict__ hs, const float* __restrict__ hi,
    const float* __restrict__ r, int jstep,
    const float* __restrict__ W1, const float* __restrict__ b1,
    const float* __restrict__ W2, const float* __restrict__ b2,
    const float* __restrict__ W3, const float* __restrict__ b3,
    const float* __restrict__ Wf, const float* __restrict__ bfp,
    float* __restrict__ cur, float* __restrict__ out)
{
    __shared__ __align__(16) float W1s[128 * 260];  // rows padded 257->260 (16B-aligned)
    __shared__ __align__(16) float zs[16 * 260];
    __shared__ __align__(16) float h1s[16 * 132];
    __shared__ __align__(16) float h2s[16 * 68];
    __shared__ float prs[16 * 8];
    __shared__ float psum[16];

    const int t = threadIdx.x;
    for (int idx = t; idx < 128 * 257; idx += 256) {
        int o = idx / 257;
        int k = idx - o * 257;
        W1s[o * 260 + k] = W1[idx];
    }
    const int i16 = t & 15, og = t >> 4;
    float b1r[8];
#pragma unroll
    for (int m = 0; m < 8; ++m) b1r[m] = b1[og + 16 * m];
    float b2r[4];
#pragma unroll
    for (int m = 0; m < 4; ++m) b2r[m] = b2[og + 16 * m];
    __syncthreads();

    for (int it = 0; it < 16; ++it) {
        const int ch    = blockIdx.x * 16 + it;   // 0..4095
        const int base  = ch * 16;
        const int b     = base >> 10;
        const int qbase = base & 1023;

        // ---- stage z = [hs(128) | hi(128) | r(1)] for 16 items ----
        {
            const int ist = t >> 4, l = t & 15;
            const int q = qbase + ist;
            const float* hrow = hs + (size_t)(b * 1024 + q) * 128;
            *(float4*)&zs[ist * 260 + l * 8]     = *(const float4*)&hrow[l * 8];
            *(float4*)&zs[ist * 260 + l * 8 + 4] = *(const float4*)&hrow[l * 8 + 4];
            const float* irow = hi + (size_t)(b * 256 + (q >> 2)) * 128;
            *(float4*)&zs[ist * 260 + 128 + l * 8]     = *(const float4*)&irow[l * 8];
            *(float4*)&zs[ist * 260 + 128 + l * 8 + 4] = *(const float4*)&irow[l * 8 + 4];
            if (l == 0) zs[ist * 260 + 256] = r[b * 4 + jstep];
        }
        __syncthreads();

        // ---- h1 = relu(z @ W1^T + b1): thread (i16, og) -> outputs og+16m ----
        {
            float acc[8];
#pragma unroll
            for (int m = 0; m < 8; ++m) acc[m] = b1r[m];
#pragma unroll 4
            for (int kq = 0; kq < 64; ++kq) {
                float4 zv = *(const float4*)&zs[i16 * 260 + kq * 4];
#pragma unroll
                for (int m = 0; m < 8; ++m) {
                    float4 wv = *(const float4*)&W1s[(og + 16 * m) * 260 + kq * 4];
                    acc[m] += zv.x * wv.x + zv.y * wv.y + zv.z * wv.z + zv.w * wv.w;
                }
            }
            float zl = zs[i16 * 260 + 256];
#pragma unroll
            for (int m = 0; m < 8; ++m) {
                float v = acc[m] + zl * W1s[(og + 16 * m) * 260 + 256];
                h1s[i16 * 132 + og + 16 * m] = fmaxf(v, 0.0f);
            }
        }
        __syncthreads();

        // ---- h2 = relu(h1 @ W2^T + b2): outputs og+16m2, W2 from L1/L2 ----
        {
            float acc[4];
#pragma unroll
            for (int m = 0; m < 4; ++m) acc[m] = b2r[m];
#pragma unroll 4
            for (int kq = 0; kq < 32; ++kq) {
                float4 hv = *(const float4*)&h1s[i16 * 132 + kq * 4];
#pragma unroll
                for (int m = 0; m < 4; ++m) {
                    float4 wv = *(const float4*)&W2[(size_t)(og + 16 * m) * 128 + kq * 4];
                    acc[m] += hv.x * wv.x + hv.y * wv.y + hv.z * wv.z + hv.w * wv.w;
                }
            }
#pragma unroll
            for (int m = 0; m < 4; ++m)
                h2s[i16 * 68 + og + 16 * m] = fmaxf(acc[m], 0.0f);
        }
        __syncthreads();

        // ---- pr = h2 @ W3^T + b3 ; cur <- pr (raw); prs <- relu(pr)*Wf ----
        if (t < 128) {
            const int ii = t & 15, c = t >> 4;
            float acc = b3[c];
#pragma unroll
            for (int kq = 0; kq < 16; ++kq) {
                float4 hv = *(const float4*)&h2s[ii * 68 + kq * 4];
                float4 wv = *(const float4*)&W3[c * 64 + kq * 4];
                acc += hv.x * wv.x + hv.y * wv.y + hv.z * wv.z + hv.w * wv.w;
            }
            const int q = qbase + ii;
            cur[(size_t)(b * 1024 + q) * 8 + c] = acc;            // next roll's input
            prs[ii * 8 + c] = fmaxf(acc, 0.0f) * Wf[c];
        }
        __syncthreads();
        if (t < 16) {
            float s = bfp[0];
#pragma unroll
            for (int c = 0; c < 8; ++c) s += prs[t * 8 + c];
            psum[t] = s;
        }
        __syncthreads();
        if (t < 4) {   // sum 4 ct-items per n; includes Ct*bf as in reference
            float v = psum[t * 4] + psum[t * 4 + 1] + psum[t * 4 + 2] + psum[t * 4 + 3];
            const int n = (qbase >> 2) + t;
            out[(size_t)(b * 256 + n) * 4 + jstep] = v;
        }
        __syncthreads();   // before next chunk overwrites zs
    }
}

extern "C" void kernel_launch(void* const* d_in, const int* in_sizes, int n_in,
                              void* d_out, int out_size, void* d_ws, size_t ws_size,
                              hipStream_t stream)
{
    const float* x   = (const float*)d_in[0];
    const float* hi  = (const float*)d_in[1];
    const float* r   = (const float*)d_in[2];
    const float* Wih = (const float*)d_in[3];
    const float* Whh = (const float*)d_in[4];
    const float* bih = (const float*)d_in[5];
    const float* bhh = (const float*)d_in[6];
    const float* W1  = (const float*)d_in[7];
    const float* b1  = (const float*)d_in[8];
    const float* W2  = (const float*)d_in[9];
    const float* b2  = (const float*)d_in[10];
    const float* W3  = (const float*)d_in[11];
    const float* b3  = (const float*)d_in[12];
    const float* Wf  = (const float*)d_in[13];
    const float* bf  = (const float*)d_in[14];
    float* out = (float*)d_out;

    float* cur = (float*)d_ws;          // 524288 floats (2 MB)
    float* hs  = cur + 524288;          // 8388608 floats (32 MB)

    init_cur_k<<<2048, 256, 0, stream>>>(x, cur);
    for (int j = 0; j < 4; ++j) {
        lstm_roll_k<<<256, 512, 0, stream>>>(cur, Wih, Whh, bih, bhh, hs);
        mlp_roll_k<<<256, 256, 0, stream>>>(hs, hi, r, j, W1, b1, W2, b2,
                                            W3, b3, Wf, bf, cur, out);
    }
}